// Round 3
// baseline (379.811 us; speedup 1.0000x reference)
//
#include <hip/hip_runtime.h>
#include <hip/hip_bf16.h>

#define N_RAYS 262144
#define N_PTS  64
#define FAR_DELTA 1e10f

#define RPB 64          // rays per block == threads per block (ONE wave)
#define ST  8           // samples per tile
#define NT  (N_PTS/ST)  // 8 tiles

// Padded word strides, multiples of 4 (16B-aligned for b128), bank-group
// stride (stride/4) coprime with 8 -> conflict-free column b128 reads.
#define DS_STRIDE 12    // 8 data + 4 pad words  (group stride 3)
#define FT_STRIDE 28    // 24 data + 4 pad words (group stride 7)

__global__ __launch_bounds__(64, 3) void volume_render_kernel(
    const float* __restrict__ density,       // (N, 64, 1)
    const float* __restrict__ depth_values,  // (N, 64)
    const float* __restrict__ rays_feature,  // (N, 64, 3)
    float* __restrict__ out)                 // feature (N*3) then depth (N)
{
    // 13,312 B total -> ~12 blocks/CU
    __shared__ float s_dens[RPB * DS_STRIDE];
    __shared__ float s_dep [RPB * DS_STRIDE];
    __shared__ float s_feat[RPB * FT_STRIDE];

    const int t    = threadIdx.x;        // one ray per thread
    const int ray0 = blockIdx.x * RPB;

    float T = 1.0f;
    float ax = 0.f, ay = 0.f, az = 0.f, ad = 0.f;
    float sig_p = 0.f, d_p = 0.f, fx_p = 0.f, fy_p = 0.f, fz_p = 0.f;

    // NOTE: no __syncthreads anywhere. Block == one wave, so LDS is
    // wave-private; DS ops from one wave execute in order and the compiler
    // inserts the vmcnt/lgkmcnt waits for the load->write->read chain.
    // This lets next tile's global loads issue during this tile's compute.
    #pragma unroll
    for (int tile = 0; tile < NT; ++tile) {
        const int s0 = tile * ST;

        // ---- stage density & depth: 64 rays x 8 floats = 128 float4 each ----
        #pragma unroll
        for (int i = 0; i < 2; ++i) {
            const int flat = i * 64 + t;        // 0..127
            const int r = flat >> 1;            // ray-local
            const int q = flat & 1;             // which float4 of the 8-float chunk
            const size_t g = (size_t)(ray0 + r) * N_PTS + s0 + q * 4;
            const float4 dv = *(const float4*)(density + g);
            const float4 zv = *(const float4*)(depth_values + g);
            *(float4*)&s_dens[r * DS_STRIDE + q * 4] = dv;
            *(float4*)&s_dep [r * DS_STRIDE + q * 4] = zv;
        }
        // ---- stage features: 64 rays x 24 floats = 384 float4 ----
        #pragma unroll
        for (int i = 0; i < 6; ++i) {
            const int flat = i * 64 + t;        // 0..383
            const int r = flat / 6;
            const int q = flat - r * 6;         // 0..5
            const size_t g = (size_t)(ray0 + r) * (N_PTS * 3) + s0 * 3 + q * 4;
            *(float4*)&s_feat[r * FT_STRIDE + q * 4] = *(const float4*)(rays_feature + g);
        }

        // ---- consume: all LDS reads are ds_read_b128, conflict-free ----
        #pragma unroll
        for (int jj = 0; jj < 2; ++jj) {
            const float4 dq = *(const float4*)&s_dep [t * DS_STRIDE + jj * 4];
            const float4 sq = *(const float4*)&s_dens[t * DS_STRIDE + jj * 4];
            const float4 f0 = *(const float4*)&s_feat[t * FT_STRIDE + jj * 12 + 0];
            const float4 f1 = *(const float4*)&s_feat[t * FT_STRIDE + jj * 12 + 4];
            const float4 f2 = *(const float4*)&s_feat[t * FT_STRIDE + jj * 12 + 8];

            const float d [4] = {dq.x, dq.y, dq.z, dq.w};
            const float sg[4] = {sq.x, sq.y, sq.z, sq.w};
            const float fx[4] = {f0.x, f0.w, f1.z, f2.y};
            const float fy[4] = {f0.y, f1.x, f1.w, f2.z};
            const float fz[4] = {f0.z, f1.y, f2.x, f2.w};

            #pragma unroll
            for (int s = 0; s < 4; ++s) {
                if (tile > 0 || jj > 0 || s > 0) {   // folds at compile time
                    const float delta = d[s] - d_p;
                    const float e = __expf(-sig_p * delta);
                    const float w = T * (1.0f - e);
                    ax += w * fx_p; ay += w * fy_p; az += w * fz_p; ad += w * d_p;
                    T *= e;
                }
                sig_p = sg[s]; d_p = d[s];
                fx_p = fx[s]; fy_p = fy[s]; fz_p = fz[s];
            }
        }
    }

    // ---- final sample: far-plane sentinel delta ----
    {
        const float e = __expf(-sig_p * FAR_DELTA);
        const float w = T * (1.0f - e);
        ax += w * fx_p; ay += w * fy_p; az += w * fz_p; ad += w * d_p;
    }

    const int ray = ray0 + t;
    out[(size_t)ray * 3 + 0] = ax;
    out[(size_t)ray * 3 + 1] = ay;
    out[(size_t)ray * 3 + 2] = az;
    out[(size_t)N_RAYS * 3 + ray] = ad;
}

extern "C" void kernel_launch(void* const* d_in, const int* in_sizes, int n_in,
                              void* d_out, int out_size, void* d_ws, size_t ws_size,
                              hipStream_t stream) {
    const float* density      = (const float*)d_in[0];
    const float* depth_values = (const float*)d_in[1];
    const float* rays_feature = (const float*)d_in[2];
    float* out = (float*)d_out;

    const int blocks = N_RAYS / RPB;  // 4096
    volume_render_kernel<<<blocks, RPB, 0, stream>>>(
        density, depth_values, rays_feature, out);
}

// Round 4
// 374.515 us; speedup vs baseline: 1.0141x; 1.0141x over previous
//
#include <hip/hip_runtime.h>
#include <hip/hip_bf16.h>

#define N_RAYS 262144
#define N_PTS  64
#define FAR_DELTA 1e10f
#define LPR 4              // lanes per ray
#define SPL 16             // samples per lane

// No LDS. 4 lanes cooperate on one ray; each lane owns 16 consecutive samples.
// All global loads are float4; the 4 lanes of a ray cover its rows contiguously.
__global__ __launch_bounds__(256, 4) void volume_render_kernel(
    const float* __restrict__ density,       // (N, 64, 1)
    const float* __restrict__ depth_values,  // (N, 64)
    const float* __restrict__ rays_feature,  // (N, 64, 3)
    float* __restrict__ out)                 // feature (N*3) then depth (N)
{
    const int t   = threadIdx.x;
    const int sub = t & (LPR - 1);                 // lane-in-ray 0..3
    const int ray = blockIdx.x * (256 / LPR) + (t >> 2);

    const size_t sbase = (size_t)ray * N_PTS + sub * SPL;

    // ---- depth & density: 4 float4 each, fully line-covering across lanes ----
    float d[SPL], sd[SPL];
    #pragma unroll
    for (int q = 0; q < 4; ++q) {
        const float4 dv = *(const float4*)(depth_values + sbase + q * 4);
        d[q*4+0] = dv.x; d[q*4+1] = dv.y; d[q*4+2] = dv.z; d[q*4+3] = dv.w;
    }
    #pragma unroll
    for (int q = 0; q < 4; ++q) {
        const float4 sv = *(const float4*)(density + sbase + q * 4);
        sd[q*4+0] = sv.x; sd[q*4+1] = sv.y; sd[q*4+2] = sv.z; sd[q*4+3] = sv.w;
    }

    // boundary: first depth of the NEXT lane's chunk (next 16 samples)
    const float d_next0 = __shfl_down(d[0], 1, 64);

    // sd[i] = sigma_i * delta_i   (last lane of the ray uses the far sentinel)
    #pragma unroll
    for (int i = 0; i < SPL - 1; ++i) sd[i] *= (d[i+1] - d[i]);
    sd[SPL-1] *= (sub == LPR-1) ? FAR_DELTA : (d_next0 - d[SPL-1]);

    // local inclusive prefix sums (pure add chain — no exp in the recurrence)
    float P[SPL];
    P[0] = sd[0];
    #pragma unroll
    for (int i = 1; i < SPL; ++i) P[i] = P[i-1] + sd[i];

    // segmented exclusive scan of lane totals across the 4 lanes of this ray.
    // Lane sub==3's total contains the 1e10 sentinel; the masking guarantees
    // it never crosses into the next ray's lanes.
    float s = P[SPL-1];
    float u = __shfl_up(s, 1, 64); if (sub >= 1) s += u;
    u       = __shfl_up(s, 2, 64); if (sub >= 2) s += u;
    float B = __shfl_up(s, 1, 64); if (sub == 0) B = 0.0f;

    // weights: w_i = exp(-(B+P[i-1])) - exp(-(B+P[i])) — 17 INDEPENDENT exps
    float w[SPL];
    float Xprev = __expf(-B);
    #pragma unroll
    for (int i = 0; i < SPL; ++i) {
        const float Xi = __expf(-(B + P[i]));
        w[i] = Xprev - Xi;
        Xprev = Xi;
    }

    float ax = 0.f, ay = 0.f, az = 0.f, ad = 0.f;
    #pragma unroll
    for (int i = 0; i < SPL; ++i) ad += w[i] * d[i];

    // ---- features: 12 float4 per lane, consumed group-by-group ----
    const float* fbase = rays_feature + (size_t)ray * (N_PTS * 3) + sub * (SPL * 3);
    #pragma unroll
    for (int g = 0; g < 4; ++g) {          // 4 samples / 3 float4 per group
        const float4 f0 = *(const float4*)(fbase + g * 12 + 0);
        const float4 f1 = *(const float4*)(fbase + g * 12 + 4);
        const float4 f2 = *(const float4*)(fbase + g * 12 + 8);
        const int i0 = g * 4;
        ax += w[i0+0]*f0.x; ay += w[i0+0]*f0.y; az += w[i0+0]*f0.z;
        ax += w[i0+1]*f0.w; ay += w[i0+1]*f1.x; az += w[i0+1]*f1.y;
        ax += w[i0+2]*f1.z; ay += w[i0+2]*f1.w; az += w[i0+2]*f2.x;
        ax += w[i0+3]*f2.y; ay += w[i0+3]*f2.z; az += w[i0+3]*f2.w;
    }

    // reduce the 4 accumulators across the ray's 4 lanes (xor 1,2 stay in-group)
    ax += __shfl_xor(ax, 1, 64); ay += __shfl_xor(ay, 1, 64);
    az += __shfl_xor(az, 1, 64); ad += __shfl_xor(ad, 1, 64);
    ax += __shfl_xor(ax, 2, 64); ay += __shfl_xor(ay, 2, 64);
    az += __shfl_xor(az, 2, 64); ad += __shfl_xor(ad, 2, 64);

    if (sub == 0) {
        out[(size_t)ray * 3 + 0] = ax;
        out[(size_t)ray * 3 + 1] = ay;
        out[(size_t)ray * 3 + 2] = az;
        out[(size_t)N_RAYS * 3 + ray] = ad;
    }
}

extern "C" void kernel_launch(void* const* d_in, const int* in_sizes, int n_in,
                              void* d_out, int out_size, void* d_ws, size_t ws_size,
                              hipStream_t stream) {
    const float* density      = (const float*)d_in[0];
    const float* depth_values = (const float*)d_in[1];
    const float* rays_feature = (const float*)d_in[2];
    float* out = (float*)d_out;

    const int blocks = N_RAYS / (256 / LPR);  // 4096
    volume_render_kernel<<<blocks, 256, 0, stream>>>(
        density, depth_values, rays_feature, out);
}